// Round 14
// baseline (198.017 us; speedup 1.0000x reference)
//
#include <hip/hip_runtime.h>

#define D 128
#define TN 64
#define NC 8   // privatization copies (#XCDs)

typedef __attribute__((ext_vector_type(8))) short short8;
typedef __attribute__((ext_vector_type(4))) float f32x4;

__device__ __forceinline__ unsigned int bf16rne(float f) {
  unsigned int b = __float_as_uint(f);
  return (b + 0x7fffu + ((b >> 16) & 1u)) >> 16;
}
__device__ __forceinline__ float bf2f(unsigned int u) {
  return __uint_as_float(u << 16);
}

// ---- one-time prep: x -> bf16 rows; W[r]/loopW -> bf16 transposed XOR-swizzled;
//      zero cnt8+rowctr8 ----
__global__ __launch_bounds__(256) void rgc_prep(
    const float* __restrict__ x, const float* __restrict__ W,
    const float* __restrict__ loopW, unsigned short* __restrict__ xb,
    unsigned short* __restrict__ WT, uint4* __restrict__ zbase,
    long long zb16, int R, long long total8, int xblocks, int wblocks)
{
  if ((int)blockIdx.x < xblocks) {
    long long i = (long long)blockIdx.x * 256 + threadIdx.x;
    if (i >= total8) return;
    float4 v0 = ((const float4*)x)[i * 2];
    float4 v1 = ((const float4*)x)[i * 2 + 1];
    uint4 u;
    u.x = bf16rne(v0.x) | (bf16rne(v0.y) << 16);
    u.y = bf16rne(v0.z) | (bf16rne(v0.w) << 16);
    u.z = bf16rne(v1.x) | (bf16rne(v1.y) << 16);
    u.w = bf16rne(v1.z) | (bf16rne(v1.w) << 16);
    ((uint4*)xb)[i] = u;
  } else if ((int)blockIdx.x < xblocks + wblocks) {
    int tid = (blockIdx.x - xblocks) * 256 + threadIdx.x;
    int s = tid >> 14;
    if (s > R) return;
    int rem = tid & 16383;
    int k = rem >> 7;
    int c = rem & 127;
    float v = (s < R) ? W[(size_t)s * D * D + k * D + c] : loopW[k * D + c];
    unsigned int u = bf16rne(v);
    unsigned int off = ((unsigned int)(c * D + k) * 2u) ^ (((unsigned int)(c & 7)) << 4);
    *(unsigned short*)((char*)WT + (size_t)s * D * D * 2 + off) = (unsigned short)u;
  } else {
    long long i = (long long)(blockIdx.x - xblocks - wblocks) * 256 + threadIdx.x;
    if (i < zb16) zbase[i] = make_uint4(0, 0, 0, 0);
  }
}

// ---- hist: one XCD-local atomic per edge into cnt8[(k*R+r)*N + d] ----
__global__ __launch_bounds__(256) void rgc_hist(
    const int* __restrict__ dst, int* __restrict__ cnt8, int N, int E, int R)
{
  int r = blockIdx.y;
  int e = blockIdx.x * 256 + threadIdx.x;
  if (e >= E) return;
  int k = (blockIdx.x + gridDim.x * blockIdx.y) & (NC - 1);
  int d = dst[(size_t)r * E + e];
  atomicAdd(&cnt8[((size_t)k * R + r) * N + d], 1);
}

// ---- offsets: one block per 256-node chunk; one XCD-local allocator atomic/block ----
__global__ __launch_bounds__(256) void rgc_offsets(
    const int* __restrict__ cnt8, int* __restrict__ rowctr8,
    int* __restrict__ off8, int* __restrict__ nodeptr, int* __restrict__ degv,
    int N, int E, int R, int nt256, int nchunks)
{
  __shared__ int wtot[4];
  __shared__ int wbase[4];
  __shared__ int sbase;

  int chunk = blockIdx.x;
  if (chunk >= nchunks) return;
  int kx = blockIdx.x & (NC - 1);
  int r = chunk / nt256, t = chunk - r * nt256;
  int tid = threadIdx.x;
  int wv = tid >> 6, lane = tid & 63;
  int node = t * 256 + tid;

  int ck[NC];
  int deg = 0;
  if (node < N) {
#pragma unroll
    for (int k = 0; k < NC; k++) {
      ck[k] = cnt8[((size_t)k * R + r) * N + node];
      deg += ck[k];
    }
  } else {
#pragma unroll
    for (int k = 0; k < NC; k++) ck[k] = 0;
  }
  int v = deg;
#pragma unroll
  for (int o = 1; o < 64; o <<= 1) {
    int tsh = __shfl_up(v, o, 64);
    if (lane >= o) v += tsh;
  }
  if (lane == 63) wtot[wv] = v;
  __syncthreads();
  if (tid == 0) {
    int run = 0;
#pragma unroll
    for (int i = 0; i < 4; i++) { wbase[i] = run; run += wtot[i]; }
    sbase = atomicAdd(&rowctr8[kx * R + r], run);
  }
  __syncthreads();

  if (node < N) {
    int start = (kx * R + r) * E + sbase + wbase[wv] + (v - deg);
    nodeptr[(size_t)r * N + node] = start;
    degv[(size_t)r * N + node] = deg;
    int run = start;
#pragma unroll
    for (int k = 0; k < NC; k++) {
      off8[((size_t)k * R + r) * N + node] = run;
      run += ck[k];
    }
  }
}

// ---- fill: scatter src ids; atomics stay per-copy (XCD-local) ----
__global__ __launch_bounds__(256) void rgc_fill(
    const int* __restrict__ src, const int* __restrict__ dst,
    int* __restrict__ off8, int* __restrict__ esrc, int N, int E, int R)
{
  int r = blockIdx.y;
  int e = blockIdx.x * 256 + threadIdx.x;
  if (e >= E) return;
  int k = (blockIdx.x + gridDim.x * blockIdx.y) & (NC - 1);
  int d = dst[(size_t)r * E + e];
  int pos = atomicAdd(&off8[((size_t)k * R + r) * N + d], 1);
  esrc[pos] = src[(size_t)r * E + e];
}

// ---- agg body: register-only gather (2-way unrolled) -> swizzled bf16 Ahat ----
__device__ __forceinline__ void agg_body(
    const unsigned short* __restrict__ xb, const int* __restrict__ nodeptr,
    const int* __restrict__ degv, const int* __restrict__ esrc,
    unsigned short* __restrict__ Ahat, int N, int R,
    int ltile, int r, int tile, int tx)
{
  int node0 = tile * TN;
  int grp = tx >> 4, c = tx & 15;
  char* dstp = (char*)(Ahat + ((size_t)ltile * R + r) * (TN * D));

#pragma unroll
  for (int t = 0; t < 4; t++) {
    int row = grp * 4 + t;
    int node = node0 + row;
    float a[8];
#pragma unroll
    for (int q = 0; q < 8; q++) a[q] = 0.f;
    int deg = 0;
    if (node < N) {
      int st = nodeptr[(size_t)r * N + node];
      deg = degv[(size_t)r * N + node];
      int j = 0;
      for (; j + 2 <= deg; j += 2) {
        int s0 = esrc[st + j];
        int s1 = esrc[st + j + 1];
        uint4 u0 = ((const uint4*)(xb + (size_t)s0 * D))[c];
        uint4 u1 = ((const uint4*)(xb + (size_t)s1 * D))[c];
        a[0] += bf2f(u0.x & 0xffffu) + bf2f(u1.x & 0xffffu);
        a[1] += bf2f(u0.x >> 16)     + bf2f(u1.x >> 16);
        a[2] += bf2f(u0.y & 0xffffu) + bf2f(u1.y & 0xffffu);
        a[3] += bf2f(u0.y >> 16)     + bf2f(u1.y >> 16);
        a[4] += bf2f(u0.z & 0xffffu) + bf2f(u1.z & 0xffffu);
        a[5] += bf2f(u0.z >> 16)     + bf2f(u1.z >> 16);
        a[6] += bf2f(u0.w & 0xffffu) + bf2f(u1.w & 0xffffu);
        a[7] += bf2f(u0.w >> 16)     + bf2f(u1.w >> 16);
      }
      if (j < deg) {
        int s0 = esrc[st + j];
        uint4 u0 = ((const uint4*)(xb + (size_t)s0 * D))[c];
        a[0] += bf2f(u0.x & 0xffffu); a[1] += bf2f(u0.x >> 16);
        a[2] += bf2f(u0.y & 0xffffu); a[3] += bf2f(u0.y >> 16);
        a[4] += bf2f(u0.z & 0xffffu); a[5] += bf2f(u0.z >> 16);
        a[6] += bf2f(u0.w & 0xffffu); a[7] += bf2f(u0.w >> 16);
      }
    }
    float sc = 1.0f / fmaxf((float)deg, 1.0f);
    uint4 o;
    o.x = bf16rne(a[0] * sc) | (bf16rne(a[1] * sc) << 16);
    o.y = bf16rne(a[2] * sc) | (bf16rne(a[3] * sc) << 16);
    o.z = bf16rne(a[4] * sc) | (bf16rne(a[5] * sc) << 16);
    o.w = bf16rne(a[6] * sc) | (bf16rne(a[7] * sc) << 16);
    unsigned int off =
        ((unsigned int)(row * 256 + c * 16)) ^ (((unsigned int)(row & 7)) << 4);
    *(uint4*)(dstp + off) = o;
  }
}

// ---- gemm body (LDS-staged, proven) ----
__device__ __forceinline__ void gemm_body(
    const unsigned short* __restrict__ xb, const unsigned short* __restrict__ WT,
    const unsigned short* __restrict__ Ahat, float* __restrict__ out,
    int N, int R, int ltile, int tile, int tx)
{
  __shared__ char Ab[TN * D * 2];  // 16 KB
  __shared__ char Wb[D * D * 2];   // 32 KB

  int node0 = tile * TN;
  int lane = tx & 63;
  int w = tx >> 6;

  f32x4 acc[8];
#pragma unroll
  for (int i = 0; i < 8; i++) acc[i] = (f32x4){0.f, 0.f, 0.f, 0.f};

  for (int s = 0; s <= R; s++) {
    bool is_loop = (s == R);
    if (!is_loop) {
      const float4* asrc = (const float4*)(Ahat + ((size_t)ltile * R + s) * (TN * D));
#pragma unroll
      for (int i = 0; i < 4; i++)
        ((float4*)Ab)[tx + i * 256] = asrc[tx + i * 256];
    } else {
#pragma unroll
      for (int it = 0; it < 4; it++) {
        int i = tx + it * 256;
        int row = i >> 4, c16 = i & 15;
        int node = node0 + row;
        uint4 u = make_uint4(0, 0, 0, 0);
        if (node < N) u = ((const uint4*)(xb + (size_t)node * D))[c16];
        unsigned int off =
            ((unsigned int)(row * 256 + c16 * 16)) ^ (((unsigned int)(row & 7)) << 4);
        *(uint4*)(Ab + off) = u;
      }
    }
    const float4* wsrc = (const float4*)(WT + (size_t)s * D * D);
#pragma unroll
    for (int i = 0; i < 8; i++)
      ((float4*)Wb)[tx + i * 256] = wsrc[tx + i * 256];
    __syncthreads();

    int rA = w * 16 + (lane & 15);
    unsigned int mA = (unsigned int)((rA & 7) << 4);
    unsigned int kof = (unsigned int)((lane >> 4) * 16);
    short8 afr[4];
#pragma unroll
    for (int kk = 0; kk < 4; kk++)
      afr[kk] = *(const short8*)(Ab + rA * 256 + (((unsigned int)(kk * 64) + kof) ^ mA));
#pragma unroll
    for (int ct = 0; ct < 8; ct++) {
      int rB = ct * 16 + (lane & 15);
      unsigned int mB = (unsigned int)((rB & 7) << 4);
#pragma unroll
      for (int kk = 0; kk < 4; kk++) {
        short8 b = *(const short8*)(Wb + rB * 256 + (((unsigned int)(kk * 64) + kof) ^ mB));
        acc[ct] = __builtin_amdgcn_mfma_f32_16x16x32_bf16(afr[kk], b, acc[ct], 0, 0, 0);
      }
    }
    __syncthreads();
  }

  int colb = lane & 15;
  int rowb = (lane >> 4) * 4;
#pragma unroll
  for (int ct = 0; ct < 8; ct++) {
#pragma unroll
    for (int j = 0; j < 4; j++) {
      int node = node0 + w * 16 + rowb + j;
      if (node < N)
        out[(size_t)node * D + ct * 16 + colb] = fmaxf(acc[ct][j], 0.f);
    }
  }
}

// ---- standalone kernels ----
__global__ __launch_bounds__(256) void rgc_agg(
    const unsigned short* __restrict__ xb, const int* __restrict__ nodeptr,
    const int* __restrict__ degv, const int* __restrict__ esrc,
    unsigned short* __restrict__ Ahat, int N, int R, int tile0)
{
  agg_body(xb, nodeptr, degv, esrc, Ahat, N, R,
           blockIdx.x, blockIdx.y, tile0 + blockIdx.x, threadIdx.x);
}

__global__ __launch_bounds__(256) void rgc_gemm(
    const unsigned short* __restrict__ xb, const unsigned short* __restrict__ WT,
    const unsigned short* __restrict__ Ahat, float* __restrict__ out,
    int N, int R, int tile0)
{
  gemm_body(xb, WT, Ahat, out, N, R, blockIdx.x, tile0 + blockIdx.x, threadIdx.x);
}

// ---- combo: gemm(chunk c) blocks interleaved with agg(chunk c+1) blocks.
// grid = (R+1, max(ct_gemm, ct_agg)); x==0 -> gemm, x>=1 -> agg relation x-1.
// x varies fastest in dispatch order -> 1:R mix resident on every CU. ----
__global__ __launch_bounds__(256) void rgc_combo(
    const unsigned short* __restrict__ xb, const unsigned short* __restrict__ WT,
    const unsigned short* __restrict__ AhatR, unsigned short* __restrict__ AhatW,
    const int* __restrict__ nodeptr, const int* __restrict__ degv,
    const int* __restrict__ esrc, float* __restrict__ out,
    int N, int R, int ct_gemm, int tile0_gemm, int ct_agg, int tile0_agg)
{
  int s = blockIdx.x;
  int t = blockIdx.y;
  if (s == 0) {
    if (t < ct_gemm)
      gemm_body(xb, WT, AhatR, out, N, R, t, tile0_gemm + t, threadIdx.x);
  } else {
    if (t < ct_agg)
      agg_body(xb, nodeptr, degv, esrc, AhatW, N, R, t, s - 1, tile0_agg + t,
               threadIdx.x);
  }
}

extern "C" void kernel_launch(void* const* d_in, const int* in_sizes, int n_in,
                              void* d_out, int out_size, void* d_ws, size_t ws_size,
                              hipStream_t stream)
{
  const float* x     = (const float*)d_in[0];
  const float* W     = (const float*)d_in[1];
  const float* loopW = (const float*)d_in[2];
  const int*   src   = (const int*)d_in[3];
  const int*   dst   = (const int*)d_in[4];
  float* out = (float*)d_out;

  int N = in_sizes[0] / D;        // 100000
  int R = in_sizes[1] / (D * D);  // 4
  int E = in_sizes[3] / R;        // 160000
  int ntiles = (N + TN - 1) / TN;
  int ctmax = (ntiles + 1) / 2;   // 2 chunks

  // layout: cnt8 | rowctr8 | off8 | nodeptr | degv | esrc[NC*R*E] | WT | xb | Ahat0 | Ahat1
  size_t o_cnt8  = 0;
  size_t o_rowc  = o_cnt8 + (size_t)NC * R * N * 4;
  size_t o_off8  = (o_rowc + (size_t)NC * R * 4 + 15) & ~(size_t)15;
  size_t o_np    = (o_off8 + (size_t)NC * R * N * 4 + 15) & ~(size_t)15;
  size_t o_deg   = (o_np + (size_t)R * N * 4 + 15) & ~(size_t)15;
  size_t o_esrc  = (o_deg + (size_t)R * N * 4 + 15) & ~(size_t)15;
  size_t o_wt    = (o_esrc + (size_t)NC * R * E * 4 + 15) & ~(size_t)15;
  size_t o_xb    = (o_wt + (size_t)(R + 1) * D * D * 2 + 15) & ~(size_t)15;
  size_t o_ahat  = (o_xb + (size_t)N * D * 2 + 15) & ~(size_t)15;

  char* wsb = (char*)d_ws;
  int*  cnt8    = (int*)(wsb + o_cnt8);
  int*  rowctr8 = (int*)(wsb + o_rowc);
  int*  off8    = (int*)(wsb + o_off8);
  int*  nodeptr = (int*)(wsb + o_np);
  int*  degv    = (int*)(wsb + o_deg);
  int*  esrc    = (int*)(wsb + o_esrc);
  unsigned short* WT    = (unsigned short*)(wsb + o_wt);
  unsigned short* xb    = (unsigned short*)(wsb + o_xb);
  unsigned short* Ahat0 = (unsigned short*)(wsb + o_ahat);
  unsigned short* Ahat1 = Ahat0 + (size_t)ctmax * R * TN * D;

  long long total8 = (long long)N * D / 8;
  int xblocks = (int)((total8 + 255) / 256);
  int wblocks = ((R + 1) * D * D + 255) / 256;
  long long zb16 = (long long)(o_off8 - o_cnt8) / 16;
  int zblocks = (int)((zb16 + 255) / 256);
  rgc_prep<<<xblocks + wblocks + zblocks, 256, 0, stream>>>(
      x, W, loopW, xb, WT, (uint4*)wsb, zb16, R, total8, xblocks, wblocks);

  dim3 egrid((E + 255) / 256, R);
  rgc_hist<<<egrid, 256, 0, stream>>>(dst, cnt8, N, E, R);
  int nt256 = (N + 255) / 256;
  int nchunks = R * nt256;
  rgc_offsets<<<nchunks, 256, 0, stream>>>(
      cnt8, rowctr8, off8, nodeptr, degv, N, E, R, nt256, nchunks);
  rgc_fill<<<egrid, 256, 0, stream>>>(src, dst, off8, esrc, N, E, R);

  int ct0 = ntiles < ctmax ? ntiles : ctmax;
  int ct1 = ntiles - ct0;

  dim3 agrid0(ct0, R);
  rgc_agg<<<agrid0, 256, 0, stream>>>(xb, nodeptr, degv, esrc, Ahat0, N, R, 0);
  if (ct1 > 0) {
    dim3 cgrid(R + 1, ct0 > ct1 ? ct0 : ct1);
    rgc_combo<<<cgrid, 256, 0, stream>>>(xb, WT, Ahat0, Ahat1, nodeptr, degv, esrc,
                                         out, N, R, ct0, 0, ct1, ct0);
    rgc_gemm<<<ct1, 256, 0, stream>>>(xb, WT, Ahat1, out, N, R, ct0);
  } else {
    rgc_gemm<<<ct0, 256, 0, stream>>>(xb, WT, Ahat0, out, N, R, 0);
  }
}

// Round 15
// 184.802 us; speedup vs baseline: 1.0715x; 1.0715x over previous
//
#include <hip/hip_runtime.h>

#define D 128
#define TN 64
#define NC 8   // privatization copies (#XCDs)

typedef __attribute__((ext_vector_type(8))) short short8;
typedef __attribute__((ext_vector_type(4))) float f32x4;

__device__ __forceinline__ unsigned int bf16rne(float f) {
  unsigned int b = __float_as_uint(f);
  return (b + 0x7fffu + ((b >> 16) & 1u)) >> 16;
}
__device__ __forceinline__ float bf2f(unsigned int u) {
  return __uint_as_float(u << 16);
}

// ---- one-time prep: x -> bf16 rows; W[r]/loopW -> bf16 transposed XOR-swizzled;
//      zero cnt8+rowctr8 ----
__global__ __launch_bounds__(256) void rgc_prep(
    const float* __restrict__ x, const float* __restrict__ W,
    const float* __restrict__ loopW, unsigned short* __restrict__ xb,
    unsigned short* __restrict__ WT, uint4* __restrict__ zbase,
    long long zb16, int R, long long total8, int xblocks, int wblocks)
{
  if ((int)blockIdx.x < xblocks) {
    long long i = (long long)blockIdx.x * 256 + threadIdx.x;
    if (i >= total8) return;
    float4 v0 = ((const float4*)x)[i * 2];
    float4 v1 = ((const float4*)x)[i * 2 + 1];
    uint4 u;
    u.x = bf16rne(v0.x) | (bf16rne(v0.y) << 16);
    u.y = bf16rne(v0.z) | (bf16rne(v0.w) << 16);
    u.z = bf16rne(v1.x) | (bf16rne(v1.y) << 16);
    u.w = bf16rne(v1.z) | (bf16rne(v1.w) << 16);
    ((uint4*)xb)[i] = u;
  } else if ((int)blockIdx.x < xblocks + wblocks) {
    int tid = (blockIdx.x - xblocks) * 256 + threadIdx.x;
    int s = tid >> 14;
    if (s > R) return;
    int rem = tid & 16383;
    int k = rem >> 7;
    int c = rem & 127;
    float v = (s < R) ? W[(size_t)s * D * D + k * D + c] : loopW[k * D + c];
    unsigned int u = bf16rne(v);
    unsigned int off = ((unsigned int)(c * D + k) * 2u) ^ (((unsigned int)(c & 7)) << 4);
    *(unsigned short*)((char*)WT + (size_t)s * D * D * 2 + off) = (unsigned short)u;
  } else {
    long long i = (long long)(blockIdx.x - xblocks - wblocks) * 256 + threadIdx.x;
    if (i < zb16) zbase[i] = make_uint4(0, 0, 0, 0);
  }
}

// ---- hist: one XCD-local atomic per edge into cnt8[(k*R+r)*N + d] ----
__global__ __launch_bounds__(256) void rgc_hist(
    const int* __restrict__ dst, int* __restrict__ cnt8, int N, int E, int R)
{
  int r = blockIdx.y;
  int e = blockIdx.x * 256 + threadIdx.x;
  if (e >= E) return;
  int k = (blockIdx.x + gridDim.x * blockIdx.y) & (NC - 1);
  int d = dst[(size_t)r * E + e];
  atomicAdd(&cnt8[((size_t)k * R + r) * N + d], 1);
}

// ---- offsets: one block per 256-node chunk; one XCD-local allocator atomic/block ----
__global__ __launch_bounds__(256) void rgc_offsets(
    const int* __restrict__ cnt8, int* __restrict__ rowctr8,
    int* __restrict__ off8, int2* __restrict__ npd,
    int N, int E, int R, int nt256, int nchunks)
{
  __shared__ int wtot[4];
  __shared__ int wbase[4];
  __shared__ int sbase;

  int chunk = blockIdx.x;
  if (chunk >= nchunks) return;
  int kx = blockIdx.x & (NC - 1);
  int r = chunk / nt256, t = chunk - r * nt256;
  int tid = threadIdx.x;
  int wv = tid >> 6, lane = tid & 63;
  int node = t * 256 + tid;

  int ck[NC];
  int deg = 0;
  if (node < N) {
#pragma unroll
    for (int k = 0; k < NC; k++) {
      ck[k] = cnt8[((size_t)k * R + r) * N + node];
      deg += ck[k];
    }
  } else {
#pragma unroll
    for (int k = 0; k < NC; k++) ck[k] = 0;
  }
  int v = deg;
#pragma unroll
  for (int o = 1; o < 64; o <<= 1) {
    int tsh = __shfl_up(v, o, 64);
    if (lane >= o) v += tsh;
  }
  if (lane == 63) wtot[wv] = v;
  __syncthreads();
  if (tid == 0) {
    int run = 0;
#pragma unroll
    for (int i = 0; i < 4; i++) { wbase[i] = run; run += wtot[i]; }
    sbase = atomicAdd(&rowctr8[kx * R + r], run);
  }
  __syncthreads();

  if (node < N) {
    int start = (kx * R + r) * E + sbase + wbase[wv] + (v - deg);
    npd[(size_t)r * N + node] = make_int2(start, deg);
    int run = start;
#pragma unroll
    for (int k = 0; k < NC; k++) {
      off8[((size_t)k * R + r) * N + node] = run;
      run += ck[k];
    }
  }
}

// ---- fill: scatter src ids; atomics stay per-copy (XCD-local) ----
__global__ __launch_bounds__(256) void rgc_fill(
    const int* __restrict__ src, const int* __restrict__ dst,
    int* __restrict__ off8, int* __restrict__ esrc, int N, int E, int R)
{
  int r = blockIdx.y;
  int e = blockIdx.x * 256 + threadIdx.x;
  if (e >= E) return;
  int k = (blockIdx.x + gridDim.x * blockIdx.y) & (NC - 1);
  int d = dst[(size_t)r * E + e];
  int pos = atomicAdd(&off8[((size_t)k * R + r) * N + d], 1);
  esrc[pos] = src[(size_t)r * E + e];
}

// ---- aggregation: register-only gather (2-way unrolled) -> swizzled bf16 Ahat ----
__global__ __launch_bounds__(256) void rgc_agg(
    const unsigned short* __restrict__ xb, const int2* __restrict__ npd,
    const int* __restrict__ esrc, unsigned short* __restrict__ Ahat,
    int N, int R, int tile0)
{
  int tx = threadIdx.x;
  int ltile = blockIdx.x;
  int tile = tile0 + ltile;
  int r = blockIdx.y;
  int node0 = tile * TN;
  int grp = tx >> 4, c = tx & 15;
  char* dstp = (char*)(Ahat + ((size_t)ltile * R + r) * (TN * D));

#pragma unroll
  for (int t = 0; t < 4; t++) {
    int row = grp * 4 + t;
    int node = node0 + row;
    float a[8];
#pragma unroll
    for (int q = 0; q < 8; q++) a[q] = 0.f;
    int deg = 0;
    if (node < N) {
      int2 sd = npd[(size_t)r * N + node];
      int st = sd.x;
      deg = sd.y;
      int j = 0;
      for (; j + 2 <= deg; j += 2) {
        int s0 = esrc[st + j];
        int s1 = esrc[st + j + 1];
        uint4 u0 = ((const uint4*)(xb + (size_t)s0 * D))[c];
        uint4 u1 = ((const uint4*)(xb + (size_t)s1 * D))[c];
        a[0] += bf2f(u0.x & 0xffffu) + bf2f(u1.x & 0xffffu);
        a[1] += bf2f(u0.x >> 16)     + bf2f(u1.x >> 16);
        a[2] += bf2f(u0.y & 0xffffu) + bf2f(u1.y & 0xffffu);
        a[3] += bf2f(u0.y >> 16)     + bf2f(u1.y >> 16);
        a[4] += bf2f(u0.z & 0xffffu) + bf2f(u1.z & 0xffffu);
        a[5] += bf2f(u0.z >> 16)     + bf2f(u1.z >> 16);
        a[6] += bf2f(u0.w & 0xffffu) + bf2f(u1.w & 0xffffu);
        a[7] += bf2f(u0.w >> 16)     + bf2f(u1.w >> 16);
      }
      if (j < deg) {
        int s0 = esrc[st + j];
        uint4 u0 = ((const uint4*)(xb + (size_t)s0 * D))[c];
        a[0] += bf2f(u0.x & 0xffffu); a[1] += bf2f(u0.x >> 16);
        a[2] += bf2f(u0.y & 0xffffu); a[3] += bf2f(u0.y >> 16);
        a[4] += bf2f(u0.z & 0xffffu); a[5] += bf2f(u0.z >> 16);
        a[6] += bf2f(u0.w & 0xffffu); a[7] += bf2f(u0.w >> 16);
      }
    }
    float sc = 1.0f / fmaxf((float)deg, 1.0f);
    uint4 o;
    o.x = bf16rne(a[0] * sc) | (bf16rne(a[1] * sc) << 16);
    o.y = bf16rne(a[2] * sc) | (bf16rne(a[3] * sc) << 16);
    o.z = bf16rne(a[4] * sc) | (bf16rne(a[5] * sc) << 16);
    o.w = bf16rne(a[6] * sc) | (bf16rne(a[7] * sc) << 16);
    unsigned int off =
        ((unsigned int)(row * 256 + c * 16)) ^ (((unsigned int)(row & 7)) << 4);
    *(uint4*)(dstp + off) = o;
  }
}

// ---- GEMM (LDS-staged, rebalanced wave decomposition):
// wave w owns ALL 4 row-tiles x col-tiles {2w, 2w+1}:
// 16 A-loads + 8 B-loads (was 4+32) per phase for the same 32 MFMA. ----
__global__ __launch_bounds__(256) void rgc_gemm(
    const unsigned short* __restrict__ xb, const unsigned short* __restrict__ WT,
    const unsigned short* __restrict__ Ahat, float* __restrict__ out,
    int N, int R, int tile0)
{
  __shared__ char Ab[TN * D * 2];  // 16 KB
  __shared__ char Wb[D * D * 2];   // 32 KB

  int tx = threadIdx.x;
  int ltile = blockIdx.x;
  int tile = tile0 + ltile;
  int node0 = tile * TN;
  int lane = tx & 63;
  int w = tx >> 6;

  f32x4 acc[4][2];
#pragma unroll
  for (int i = 0; i < 4; i++)
#pragma unroll
    for (int j = 0; j < 2; j++) acc[i][j] = (f32x4){0.f, 0.f, 0.f, 0.f};

  unsigned int kof = (unsigned int)((lane >> 4) * 16);

  for (int s = 0; s <= R; s++) {
    bool is_loop = (s == R);
    if (!is_loop) {
      const float4* asrc = (const float4*)(Ahat + ((size_t)ltile * R + s) * (TN * D));
#pragma unroll
      for (int i = 0; i < 4; i++)
        ((float4*)Ab)[tx + i * 256] = asrc[tx + i * 256];
    } else {
#pragma unroll
      for (int it = 0; it < 4; it++) {
        int i = tx + it * 256;
        int row = i >> 4, c16 = i & 15;
        int node = node0 + row;
        uint4 u = make_uint4(0, 0, 0, 0);
        if (node < N) u = ((const uint4*)(xb + (size_t)node * D))[c16];
        unsigned int off =
            ((unsigned int)(row * 256 + c16 * 16)) ^ (((unsigned int)(row & 7)) << 4);
        *(uint4*)(Ab + off) = u;
      }
    }
    const float4* wsrc = (const float4*)(WT + (size_t)s * D * D);
#pragma unroll
    for (int i = 0; i < 8; i++)
      ((float4*)Wb)[tx + i * 256] = wsrc[tx + i * 256];
    __syncthreads();

    // B fragments for this wave's two col-tiles
    short8 bfr[2][4];
#pragma unroll
    for (int ctl = 0; ctl < 2; ctl++) {
      int rB = (2 * w + ctl) * 16 + (lane & 15);
      unsigned int mB = (unsigned int)((rB & 7) << 4);
#pragma unroll
      for (int kk = 0; kk < 4; kk++)
        bfr[ctl][kk] =
            *(const short8*)(Wb + rB * 256 + (((unsigned int)(kk * 64) + kof) ^ mB));
    }
    // row-tiles
#pragma unroll
    for (int rt = 0; rt < 4; rt++) {
      int rA = rt * 16 + (lane & 15);
      unsigned int mA = (unsigned int)((rA & 7) << 4);
      short8 afr[4];
#pragma unroll
      for (int kk = 0; kk < 4; kk++)
        afr[kk] =
            *(const short8*)(Ab + rA * 256 + (((unsigned int)(kk * 64) + kof) ^ mA));
#pragma unroll
      for (int ctl = 0; ctl < 2; ctl++)
#pragma unroll
        for (int kk = 0; kk < 4; kk++)
          acc[rt][ctl] = __builtin_amdgcn_mfma_f32_16x16x32_bf16(
              afr[kk], bfr[ctl][kk], acc[rt][ctl], 0, 0, 0);
    }
    __syncthreads();
  }

  int colb = lane & 15;
  int rowb = (lane >> 4) * 4;
#pragma unroll
  for (int rt = 0; rt < 4; rt++) {
#pragma unroll
    for (int ctl = 0; ctl < 2; ctl++) {
      int ct = 2 * w + ctl;
#pragma unroll
      for (int j = 0; j < 4; j++) {
        int node = node0 + rt * 16 + rowb + j;
        if (node < N)
          out[(size_t)node * D + ct * 16 + colb] = fmaxf(acc[rt][ctl][j], 0.f);
      }
    }
  }
}

extern "C" void kernel_launch(void* const* d_in, const int* in_sizes, int n_in,
                              void* d_out, int out_size, void* d_ws, size_t ws_size,
                              hipStream_t stream)
{
  const float* x     = (const float*)d_in[0];
  const float* W     = (const float*)d_in[1];
  const float* loopW = (const float*)d_in[2];
  const int*   src   = (const int*)d_in[3];
  const int*   dst   = (const int*)d_in[4];
  float* out = (float*)d_out;

  int N = in_sizes[0] / D;        // 100000
  int R = in_sizes[1] / (D * D);  // 4
  int E = in_sizes[3] / R;        // 160000
  int ntiles = (N + TN - 1) / TN;
  int ctmax = (ntiles + 1) / 2;   // 2 chunks

  // layout: cnt8 | rowctr8 | off8 | npd(int2) | esrc[NC*R*E] | WT | xb | Ahat(chunk)
  size_t o_cnt8  = 0;
  size_t o_rowc  = o_cnt8 + (size_t)NC * R * N * 4;
  size_t o_off8  = (o_rowc + (size_t)NC * R * 4 + 15) & ~(size_t)15;
  size_t o_npd   = (o_off8 + (size_t)NC * R * N * 4 + 15) & ~(size_t)15;
  size_t o_esrc  = (o_npd + (size_t)R * N * 8 + 15) & ~(size_t)15;
  size_t o_wt    = (o_esrc + (size_t)NC * R * E * 4 + 15) & ~(size_t)15;
  size_t o_xb    = (o_wt + (size_t)(R + 1) * D * D * 2 + 15) & ~(size_t)15;
  size_t o_ahat  = (o_xb + (size_t)N * D * 2 + 15) & ~(size_t)15;

  char* wsb = (char*)d_ws;
  int*  cnt8    = (int*)(wsb + o_cnt8);
  int*  rowctr8 = (int*)(wsb + o_rowc);
  int*  off8    = (int*)(wsb + o_off8);
  int2* npd     = (int2*)(wsb + o_npd);
  int*  esrc    = (int*)(wsb + o_esrc);
  unsigned short* WT   = (unsigned short*)(wsb + o_wt);
  unsigned short* xb   = (unsigned short*)(wsb + o_xb);
  unsigned short* Ahat = (unsigned short*)(wsb + o_ahat);

  long long total8 = (long long)N * D / 8;
  int xblocks = (int)((total8 + 255) / 256);
  int wblocks = ((R + 1) * D * D + 255) / 256;
  long long zb16 = (long long)(o_off8 - o_cnt8) / 16;
  int zblocks = (int)((zb16 + 255) / 256);
  rgc_prep<<<xblocks + wblocks + zblocks, 256, 0, stream>>>(
      x, W, loopW, xb, WT, (uint4*)wsb, zb16, R, total8, xblocks, wblocks);

  dim3 egrid((E + 255) / 256, R);
  rgc_hist<<<egrid, 256, 0, stream>>>(dst, cnt8, N, E, R);
  int nt256 = (N + 255) / 256;
  int nchunks = R * nt256;
  rgc_offsets<<<nchunks, 256, 0, stream>>>(
      cnt8, rowctr8, off8, npd, N, E, R, nt256, nchunks);
  rgc_fill<<<egrid, 256, 0, stream>>>(src, dst, off8, esrc, N, E, R);

  for (int c = 0; c < 2; c++) {
    int tile0 = c * ctmax;
    int ct = (ntiles - tile0 < ctmax) ? (ntiles - tile0) : ctmax;
    if (ct <= 0) break;
    dim3 agrid(ct, R);
    rgc_agg<<<agrid, 256, 0, stream>>>(xb, npd, esrc, Ahat, N, R, tile0);
    rgc_gemm<<<ct, 256, 0, stream>>>(xb, WT, Ahat, out, N, R, tile0);
  }
}